// Round 1
// baseline (714.752 us; speedup 1.0000x reference)
//
#include <hip/hip_runtime.h>
#include <math.h>

// Problem constants (from reference): B=16, T=64, H=32, W=32, C=64
constexpr int Bc = 16, Tc = 64, Hc = 32, Wc = 32, Cc = 64;
constexpr int HWC = Hc * Wc * Cc;              // 65536 = 2^16
constexpr long long NELEM = (long long)Bc * Tc * HWC;  // 67,108,864
constexpr float DECAY_V = 0.8f;
constexpr float VTH_BASE = 0.5f;

// One thread owns 4 consecutive c-values of one (b,h,w) cell and runs the
// whole T=64 recurrence. float4 loads/stores, fully coalesced (C innermost).
__global__ __launch_bounds__(256) void alif_fwd_kernel(
    const float* __restrict__ x,             // [B,T,H,W,C]
    const float* __restrict__ hp_base_step,  // scalar
    const float* __restrict__ hp_base_decay, // scalar
    const float* __restrict__ step_w_raw,    // [H,W,C]
    const float* __restrict__ decay_w_raw,   // [H,W,C]
    const float* __restrict__ gamma,         // [H,W,C]
    const float* __restrict__ beta,          // [H,W,C]
    float* __restrict__ spikes,              // [B,T,H,W,C]
    float* __restrict__ volts)               // [B,T,H,W,C]
{
    const int tid = blockIdx.x * blockDim.x + threadIdx.x;  // 0 .. 262143
    const int c4  = tid << 2;              // element index into [B,H,W,C]
    const int b   = c4 >> 16;              // / HWC
    const int hwc = c4 & (HWC - 1);        // % HWC

    const float base_step  = *hp_base_step;   // wave-uniform scalar loads
    const float base_decay = *hp_base_decay;

    const float4 swr = *(const float4*)(step_w_raw  + hwc);
    const float4 dwr = *(const float4*)(decay_w_raw + hwc);
    const float4 gm4 = *(const float4*)(gamma       + hwc);
    const float4 bt4 = *(const float4*)(beta        + hwc);

    float gm[4]  = {gm4.x, gm4.y, gm4.z, gm4.w};
    float bt[4]  = {bt4.x, bt4.y, bt4.z, bt4.w};
    float swr_a[4] = {swr.x, swr.y, swr.z, swr.w};
    float dwr_a[4] = {dwr.x, dwr.y, dwr.z, dwr.w};

    float step_eff[4], decay_eff[4];
    float v[4]   = {0.f, 0.f, 0.f, 0.f};
    float vth[4] = {0.f, 0.f, 0.f, 0.f};

#pragma unroll
    for (int j = 0; j < 4; ++j) {
        // softplus / sigmoid in double, rounded to f32 -> correctly-rounded
        // f32 param path (matches numpy f32 to within its own exp() ulp).
        float sw = (float)log1p(exp((double)swr_a[j]));
        float dw = (float)(1.0 / (1.0 + exp(-(double)dwr_a[j])));
        step_eff[j]  = base_step * sw;
        decay_eff[j] = base_decay + (1.0f - base_decay) * dw;
    }

    const size_t base = (size_t)b * Tc * HWC + (size_t)hwc;
    const float* xp = x      + base;
    float*       sp = spikes + base;
    float*       vp = volts  + base;

#pragma unroll 4
    for (int t = 0; t < Tc; ++t) {
        const float4 xv = *(const float4*)xp;
        float xin[4] = {xv.x, xv.y, xv.z, xv.w};
        float4 so, vo;
        float sarr[4], varr[4];
#pragma unroll
        for (int j = 0; j < 4; ++j) {
            float vv      = v[j] * DECAY_V + (xin[j] * gm[j] + bt[j]);
            float vth_eff = VTH_BASE + vth[j];
            float s       = (vv - vth_eff > 0.0f) ? 1.0f : 0.0f;
            varr[j] = vv;                       // voltage BEFORE reset
            v[j]    = vv - vth_eff * s;         // soft reset
            vth[j]  = vth[j] * decay_eff[j] + s * step_eff[j];
            sarr[j] = s;
        }
        so.x = sarr[0]; so.y = sarr[1]; so.z = sarr[2]; so.w = sarr[3];
        vo.x = varr[0]; vo.y = varr[1]; vo.z = varr[2]; vo.w = varr[3];
        *(float4*)sp = so;
        *(float4*)vp = vo;
        xp += HWC; sp += HWC; vp += HWC;
    }
}

extern "C" void kernel_launch(void* const* d_in, const int* in_sizes, int n_in,
                              void* d_out, int out_size, void* d_ws, size_t ws_size,
                              hipStream_t stream) {
    // Input order per setup_inputs():
    // 0: x, 1: hp_alpha (unused in fwd), 2: hp_base_step, 3: hp_base_decay,
    // 4: step_w_raw, 5: decay_w_raw, 6: gamma, 7: beta
    const float* x             = (const float*)d_in[0];
    const float* hp_base_step  = (const float*)d_in[2];
    const float* hp_base_decay = (const float*)d_in[3];
    const float* step_w_raw    = (const float*)d_in[4];
    const float* decay_w_raw   = (const float*)d_in[5];
    const float* gamma         = (const float*)d_in[6];
    const float* beta          = (const float*)d_in[7];

    float* spikes = (float*)d_out;           // output 0: [B,T,H,W,C]
    float* volts  = spikes + NELEM;          // output 1: [B,T,H,W,C]

    const int threads = 256;
    const int total   = Bc * HWC / 4;        // 262,144 threads
    const int blocks  = total / threads;     // 1024 blocks

    alif_fwd_kernel<<<blocks, threads, 0, stream>>>(
        x, hp_base_step, hp_base_decay, step_w_raw, decay_w_raw,
        gamma, beta, spikes, volts);
}